// Round 5
// baseline (213.050 us; speedup 1.0000x reference)
//
#include <hip/hip_runtime.h>
#include <hip/hip_bf16.h>

// Problem shape: M = B*S = 8192, K = NX = 1024, N = NF = 4096
#define M_DIM 8192
#define K_DIM 1024
#define N_DIM 4096
// Block tile 128x128, BK=32, 4 waves (2x2), per-wave 64x64 via 32x32 frags.
// LDS buffer 32KB: [0,4K) A_i8 [h:2][row:128]x16B | [4K,8K) A_fp8 [kg8:4][row:128]x8B
// [8K,16K) A_bf16 [kg8:4][row:128]x16B | [16K,20K) B_i8 | [20K,24K) B_fp8 | [24K,32K) B_bf16
// Double-buffered: 64KB -> 2 blocks/CU co-resident (cross-block latency hiding).
#define BUF_BYTES 32768

typedef __attribute__((ext_vector_type(8))) short bf16x8;
typedef __attribute__((ext_vector_type(4))) int i32x4;
typedef __attribute__((ext_vector_type(16))) int i32x16;
typedef __attribute__((ext_vector_type(16))) float f32x16;

__device__ __forceinline__ short f2bf(float f) {
  unsigned u = __builtin_bit_cast(unsigned, f);
  u = (u + 0x7fffu + ((u >> 16) & 1u)) >> 16;
  return (short)u;
}

// f32 -> OCP e4m3fn, exact for our value set (small ints x 2^e)
__device__ __forceinline__ unsigned f2fp8(float v) {
  unsigned b = __builtin_bit_cast(unsigned, v);
  unsigned sg = (b >> 24) & 0x80u;
  unsigned ab = b & 0x7fffffffu;
  if (ab == 0) return sg;
  int e = (int)(ab >> 23) - 127;
  unsigned m3 = (ab >> 20) & 7u;
  if (e >= -6) return sg | (unsigned)((e + 7) << 3) | m3;
  return sg | ((8u + m3) >> (-6 - e));  // subnormal (exact for our values)
}

__device__ __forceinline__ float gelu_f(float x) {
  float u = 0.7978845608028654f * (x + 0.044715f * x * x * x);
  float e = __expf(2.0f * u);
  float t = 1.0f - 2.0f / (e + 1.0f);
  return 0.5f * x * (1.0f + t);
}

__device__ __forceinline__ void gload16(const void* g, void* l) {
  __builtin_amdgcn_global_load_lds((const __attribute__((address_space(1))) void*)g,
                                   (__attribute__((address_space(3))) void*)l, 16, 0, 0);
}

// ---------------- per-k power-of-2 weight scale ----------------
__global__ void rowmax_kernel(const float* __restrict__ w, float* __restrict__ mw) {
  int row = blockIdx.x * 4 + (threadIdx.x >> 6);
  int lane = threadIdx.x & 63;
  const float4* rp = (const float4*)(w + (size_t)row * N_DIM);
  float m = 0.0f;
#pragma unroll
  for (int it = 0; it < 16; ++it) {
    float4 v = rp[it * 64 + lane];
    m = fmaxf(m, fmaxf(fmaxf(fabsf(v.x), fabsf(v.y)), fmaxf(fabsf(v.z), fabsf(v.w))));
  }
#pragma unroll
  for (int off = 32; off > 0; off >>= 1) m = fmaxf(m, __shfl_xor(m, off, 64));
  if (lane == 0) mw[row] = exp2f(rintf(log2f(m)));
}

// ---------------- prep A: one thread per (kg16, m); 16 k-values ----------------
__global__ void prep_a_kernel(const float* __restrict__ inp, signed char* __restrict__ aqi,
                              unsigned char* __restrict__ adf, short* __restrict__ af) {
  int c = blockIdx.x * 256 + threadIdx.x;   // [kg16:64][m:8192]
  int kg = c >> 13, m = c & 8191;
  const float4* src = (const float4*)(inp + (size_t)m * K_DIM + kg * 16);
  float xs[16];
#pragma unroll
  for (int v = 0; v < 4; ++v) {
    float4 t = src[v];
    xs[v * 4 + 0] = t.x; xs[v * 4 + 1] = t.y; xs[v * 4 + 2] = t.z; xs[v * 4 + 3] = t.w;
  }
  int qi[4] = {0, 0, 0, 0};
  unsigned long long f8lo = 0ull, f8hi = 0ull;
  bf16x8 b0, b1;
#pragma unroll
  for (int j = 0; j < 16; ++j) {
    float x = xs[j];
    float s = (x > 0.f) ? 1.f : ((x < 0.f) ? -1.f : 0.f);
    float r = rintf(fabsf(x));
    int iq = (int)(s * fminf(r + 1.f, 7.f));     // in_q, exact small int
    qi[j >> 2] |= (iq & 255) << ((j & 3) * 8);
    unsigned f8 = f2fp8(s * fminf(r, 6.f));      // deq(in_q)
    if (j < 8) f8lo |= (unsigned long long)f8 << (j * 8);
    else       f8hi |= (unsigned long long)f8 << ((j - 8) * 8);
    short bb = f2bf(x);
    if (j < 8) b0[j] = bb; else b1[j - 8] = bb;
  }
  *(i32x4*)(aqi + ((size_t)kg * M_DIM + m) * 16) = (i32x4){qi[0], qi[1], qi[2], qi[3]};
  *(unsigned long long*)(adf + ((size_t)(2 * kg) * M_DIM + m) * 8) = f8lo;
  *(unsigned long long*)(adf + ((size_t)(2 * kg + 1) * M_DIM + m) * 8) = f8hi;
  *(bf16x8*)(af + ((size_t)(2 * kg) * M_DIM + m) * 8) = b0;
  *(bf16x8*)(af + ((size_t)(2 * kg + 1) * M_DIM + m) * 8) = b1;
}

// ---------------- prep W: one thread per (kg16, n) ----------------
__global__ void prep_w_kernel(const float* __restrict__ w, const float* __restrict__ mw,
                              signed char* __restrict__ wqi, unsigned char* __restrict__ wdf,
                              short* __restrict__ wf) {
  int c = blockIdx.x * 256 + threadIdx.x;   // [kg16:64][n:4096]
  int kg = c >> 12, n = c & 4095;
  int qi[4] = {0, 0, 0, 0};
  unsigned long long f8lo = 0ull, f8hi = 0ull;
  bf16x8 b0, b1;
#pragma unroll
  for (int j = 0; j < 16; ++j) {
    float wv = w[(size_t)(kg * 16 + j) * N_DIM + n];
    float sc = mw[kg * 16 + j];                  // wave-uniform
    float s = (wv > 0.f) ? 1.f : ((wv < 0.f) ? -1.f : 0.f);
    float r = rintf(fabsf(wv) * (8.0f / sc));    // exact: 8/sc is a power of 2
    int iq = (int)(s * fminf(r + 1.f, 7.f));     // w_q
    qi[j >> 2] |= (iq & 255) << ((j & 3) * 8);
    unsigned f8 = f2fp8(s * fminf(r, 6.f) * 0.125f * sc);  // deq(w_q), exact in e4m3
    if (j < 8) f8lo |= (unsigned long long)f8 << (j * 8);
    else       f8hi |= (unsigned long long)f8 << ((j - 8) * 8);
    short bb = f2bf(wv);
    if (j < 8) b0[j] = bb; else b1[j - 8] = bb;
  }
  *(i32x4*)(wqi + ((size_t)kg * N_DIM + n) * 16) = (i32x4){qi[0], qi[1], qi[2], qi[3]};
  *(unsigned long long*)(wdf + ((size_t)(2 * kg) * N_DIM + n) * 8) = f8lo;
  *(unsigned long long*)(wdf + ((size_t)(2 * kg + 1) * N_DIM + n) * 8) = f8hi;
  *(bf16x8*)(wf + ((size_t)(2 * kg) * N_DIM + n) * 8) = b0;
  *(bf16x8*)(wf + ((size_t)(2 * kg + 1) * N_DIM + n) * 8) = b1;
}

// ---------------- fused triple GEMM (i8 + fp8 + bf16) + select + GELU ----------------
__global__ __launch_bounds__(256, 2) void fused_gemm_kernel(
    const signed char* __restrict__ aqi, const unsigned char* __restrict__ adf,
    const short* __restrict__ af, const signed char* __restrict__ wqi,
    const unsigned char* __restrict__ wdf, const short* __restrict__ wf,
    const float* __restrict__ bias, float* __restrict__ out) {
  extern __shared__ char lds[];

  const int tid = threadIdx.x;
  const int wid = tid >> 6;   // 0..3
  const int lane = tid & 63;

  // XCD swizzle: 2048 blocks, 8 XCDs -> 256 contiguous tiles per XCD (bijective)
  int bid = blockIdx.x;
  bid = (bid & 7) * 256 + (bid >> 3);
  const int bm0 = (bid >> 5) * 128;   // 64 m-tiles
  const int bn0 = (bid & 31) * 128;   // 32 n-tiles

  const int wr = wid >> 1;   // 0..1 -> 64 rows
  const int wc = wid & 1;    // 0..1 -> 64 cols

  // ---- staging: 32 units of 1KB per K-step buffer, 8 per wave (uniform for vmcnt) ----
  const char* gb[8]; int gs[8]; int lo[8];
#pragma unroll
  for (int i = 0; i < 8; ++i) {
    int u = wid * 8 + i;
    lo[i] = u * 1024 + lane * 16;     // linear LDS destination
    if (u < 4) {                                        // A_i8 [h:2][row:128]x16B
      int o = u * 64 + lane; int h2 = o >> 7, row = o & 127;
      gb[i] = (const char*)aqi + ((size_t)h2 * M_DIM + bm0 + row) * 16;
      gs[i] = 32 * M_DIM;
    } else if (u < 8) {                                 // A_fp8 [kg8:4][row:128]x8B
      int kg = u - 4;
      gb[i] = (const char*)adf + ((size_t)kg * M_DIM + bm0) * 8 + lane * 16;
      gs[i] = 32 * M_DIM;
    } else if (u < 16) {                                // A_bf16 [kg8:4][row:128]x16B
      int o = (u - 8) * 64 + lane; int kg = o >> 7, row = o & 127;
      gb[i] = (const char*)af + ((size_t)kg * M_DIM + bm0 + row) * 16;
      gs[i] = 64 * M_DIM;
    } else if (u < 20) {                                // B_i8 [h:2][col:128]x16B
      int o = (u - 16) * 64 + lane; int h2 = o >> 7, col = o & 127;
      gb[i] = (const char*)wqi + ((size_t)h2 * N_DIM + bn0 + col) * 16;
      gs[i] = 32 * N_DIM;
    } else if (u < 24) {                                // B_fp8 [kg8:4][col:128]x8B
      int kg = u - 20;
      gb[i] = (const char*)wdf + ((size_t)kg * N_DIM + bn0) * 8 + lane * 16;
      gs[i] = 32 * N_DIM;
    } else {                                            // B_bf16 [kg8:4][col:128]x16B
      int o = (u - 24) * 64 + lane; int kg = o >> 7, col = o & 127;
      gb[i] = (const char*)wf + ((size_t)kg * N_DIM + bn0 + col) * 16;
      gs[i] = 64 * N_DIM;
    }
  }

  // fragment geometry (32x32 shapes): row/col = lane&31, k-half h = lane>>5
  const int h = lane >> 5;
  const int l31 = lane & 31;
  const int ra = wr * 64 + l31;
  const int rb = wc * 64 + l31;

  i32x16 acc0[2][2];
  f32x16 acc1[2][2], acc2[2][2];
  const i32x16 zi = {0, 0, 0, 0, 0, 0, 0, 0, 0, 0, 0, 0, 0, 0, 0, 0};
  const f32x16 zf = {0, 0, 0, 0, 0, 0, 0, 0, 0, 0, 0, 0, 0, 0, 0, 0};
#pragma unroll
  for (int mf = 0; mf < 2; ++mf)
#pragma unroll
    for (int nf = 0; nf < 2; ++nf) { acc0[mf][nf] = zi; acc1[mf][nf] = zf; acc2[mf][nf] = zf; }

  // prologue: tile 0 -> buf0
#pragma unroll
  for (int i = 0; i < 8; ++i) gload16(gb[i], lds + lo[i]);

  for (int t = 0; t < 32; ++t) {
    const int cb = (t & 1) * BUF_BYTES;
    if (t < 31) {
      const int nb = ((t + 1) & 1) * BUF_BYTES;
#pragma unroll
      for (int i = 0; i < 8; ++i)
        gload16(gb[i] + (size_t)(t + 1) * gs[i], lds + nb + lo[i]);
      asm volatile("s_waitcnt vmcnt(8)" ::: "memory");  // tile t landed, t+1 in flight
    } else {
      asm volatile("s_waitcnt vmcnt(0)" ::: "memory");
    }
    __builtin_amdgcn_s_barrier();
    __builtin_amdgcn_sched_barrier(0);

    const char* B = lds + cb;
    __builtin_amdgcn_s_setprio(1);
    // ---- q0: i8 sign GEMM (exact) ----
    {
      i32x4 a0[2], b0[2];
#pragma unroll
      for (int mf = 0; mf < 2; ++mf)
        a0[mf] = *(const i32x4*)(B + (h * 128 + ra + mf * 32) * 16);
#pragma unroll
      for (int nf = 0; nf < 2; ++nf)
        b0[nf] = *(const i32x4*)(B + 16384 + (h * 128 + rb + nf * 32) * 16);
#pragma unroll
      for (int mf = 0; mf < 2; ++mf)
#pragma unroll
        for (int nf = 0; nf < 2; ++nf)
          acc0[mf][nf] =
              __builtin_amdgcn_mfma_i32_32x32x32_i8(a0[mf], b0[nf], acc0[mf][nf], 0, 0, 0);
    }
    // ---- q1: fp8 dequant GEMM (exact) ----
#pragma unroll
    for (int kk = 0; kk < 2; ++kk) {
      long a1[2], b1[2];
#pragma unroll
      for (int mf = 0; mf < 2; ++mf)
        a1[mf] = *(const long*)(B + 4096 + ((kk * 2 + h) * 128 + ra + mf * 32) * 8);
#pragma unroll
      for (int nf = 0; nf < 2; ++nf)
        b1[nf] = *(const long*)(B + 20480 + ((kk * 2 + h) * 128 + rb + nf * 32) * 8);
#pragma unroll
      for (int mf = 0; mf < 2; ++mf)
#pragma unroll
        for (int nf = 0; nf < 2; ++nf)
          acc1[mf][nf] = __builtin_amdgcn_mfma_f32_32x32x16_fp8_fp8(a1[mf], b1[nf],
                                                                    acc1[mf][nf], 0, 0, 0);
    }
    // ---- q2: bf16 full GEMM ----
#pragma unroll
    for (int kk = 0; kk < 2; ++kk) {
      bf16x8 a2[2], b2[2];
#pragma unroll
      for (int mf = 0; mf < 2; ++mf)
        a2[mf] = *(const bf16x8*)(B + 8192 + ((kk * 2 + h) * 128 + ra + mf * 32) * 16);
#pragma unroll
      for (int nf = 0; nf < 2; ++nf)
        b2[nf] = *(const bf16x8*)(B + 24576 + ((kk * 2 + h) * 128 + rb + nf * 32) * 16);
#pragma unroll
      for (int mf = 0; mf < 2; ++mf)
#pragma unroll
        for (int nf = 0; nf < 2; ++nf)
          acc2[mf][nf] = __builtin_amdgcn_mfma_f32_32x32x16_bf16(a2[mf], b2[nf],
                                                                 acc2[mf][nf], 0, 0, 0);
    }
    __builtin_amdgcn_s_setprio(0);
    asm volatile("s_waitcnt lgkmcnt(0)" ::: "memory");  // all LDS reads of buf done
    __builtin_amdgcn_sched_barrier(0);
    __builtin_amdgcn_s_barrier();                       // safe to overwrite buf next iter
  }

  // ---- epilogue: select by exact integer sign, bias, GELU ----
  // 32x32 C layout: col = lane&31, row = (reg&3) + 8*(reg>>2) + 4*(lane>>5)
#pragma unroll
  for (int nf = 0; nf < 2; ++nf) {
    const int col = bn0 + rb + nf * 32;
    const float bv = bias[col];
    const float sb = (bv > 0.f) ? 1.f : ((bv < 0.f) ? -1.f : 0.f);
    const float db = sb * fminf(rintf(fabsf(bv)), 6.f);
#pragma unroll
    for (int mf = 0; mf < 2; ++mf) {
#pragma unroll
      for (int r = 0; r < 16; ++r) {
        const int row = bm0 + wr * 64 + mf * 32 + (r & 3) + 8 * (r >> 2) + 4 * h;
        float x = (acc0[mf][nf][r] < 0) ? (acc1[mf][nf][r] + db) : (acc2[mf][nf][r] + bv);
        out[(size_t)row * N_DIM + col] = gelu_f(x);
      }
    }
  }
}

extern "C" void kernel_launch(void* const* d_in, const int* in_sizes, int n_in,
                              void* d_out, int out_size, void* d_ws, size_t ws_size,
                              hipStream_t stream) {
  const float* inp = (const float*)d_in[0];
  const float* w = (const float*)d_in[1];
  const float* bias = (const float*)d_in[2];
  float* out = (float*)d_out;

  // workspace: af 16MB | wf 8MB | aqi 8MB | adf 8MB | wqi 4MB | wdf 4MB | mw 4KB
  char* p = (char*)d_ws;
  short* af = (short*)p;             p += (size_t)M_DIM * K_DIM * 2;
  short* wf = (short*)p;             p += (size_t)K_DIM * N_DIM * 2;
  signed char* aqi = (signed char*)p; p += (size_t)M_DIM * K_DIM;
  unsigned char* adf = (unsigned char*)p; p += (size_t)M_DIM * K_DIM;
  signed char* wqi = (signed char*)p; p += (size_t)K_DIM * N_DIM;
  unsigned char* wdf = (unsigned char*)p; p += (size_t)K_DIM * N_DIM;
  float* mw = (float*)p;

  const int lds_bytes = 2 * BUF_BYTES;  // 65536 -> 2 blocks/CU
  hipFuncSetAttribute((const void*)fused_gemm_kernel,
                      hipFuncAttributeMaxDynamicSharedMemorySize, lds_bytes);

  rowmax_kernel<<<K_DIM / 4, 256, 0, stream>>>(w, mw);
  prep_a_kernel<<<(M_DIM * K_DIM / 16) / 256, 256, 0, stream>>>(inp, aqi, adf, af);
  prep_w_kernel<<<(K_DIM * N_DIM / 16) / 256, 256, 0, stream>>>(w, mw, wqi, wdf, wf);
  fused_gemm_kernel<<<(M_DIM / 128) * (N_DIM / 128), 256, lds_bytes, stream>>>(
      aqi, adf, af, wqi, wdf, wf, bias, out);
}

// Round 6
// 212.971 us; speedup vs baseline: 1.0004x; 1.0004x over previous
//
#include <hip/hip_runtime.h>
#include <hip/hip_bf16.h>

// Problem shape: M = B*S = 8192, K = NX = 1024, N = NF = 4096
#define M_DIM 8192
#define K_DIM 1024
#define N_DIM 4096
// Block tile 128x128, BK=32, 4 waves (2x2), per-wave 64x64 via 32x32 frags.
// LDS buffer 32KB: [0,4K) A_i8 [h:2][row:128]x16B | [4K,8K) A_fp8 [kg8:4][row:128]x8B
// [8K,16K) A_bf16 [kg8:4][row:128]x16B | [16K,20K) B_i8 | [20K,24K) B_fp8 | [24K,32K) B_bf16
// Double-buffered: 64KB -> 2 blocks/CU co-resident (cross-block latency hiding).
#define BUF_BYTES 32768

typedef __attribute__((ext_vector_type(8))) short bf16x8;
typedef __attribute__((ext_vector_type(4))) int i32x4;
typedef __attribute__((ext_vector_type(16))) int i32x16;
typedef __attribute__((ext_vector_type(16))) float f32x16;

__device__ __forceinline__ short f2bf(float f) {
  unsigned u = __builtin_bit_cast(unsigned, f);
  u = (u + 0x7fffu + ((u >> 16) & 1u)) >> 16;
  return (short)u;
}

// f32 -> OCP e4m3fn, exact for our value set (small ints x 2^e)
__device__ __forceinline__ unsigned f2fp8(float v) {
  unsigned b = __builtin_bit_cast(unsigned, v);
  unsigned sg = (b >> 24) & 0x80u;
  unsigned ab = b & 0x7fffffffu;
  if (ab == 0) return sg;
  int e = (int)(ab >> 23) - 127;
  unsigned m3 = (ab >> 20) & 7u;
  if (e >= -6) return sg | (unsigned)((e + 7) << 3) | m3;
  return sg | ((8u + m3) >> (-6 - e));  // subnormal (exact for our values)
}

__device__ __forceinline__ float gelu_f(float x) {
  float u = 0.7978845608028654f * (x + 0.044715f * x * x * x);
  float e = __expf(2.0f * u);
  float t = 1.0f - 2.0f / (e + 1.0f);
  return 0.5f * x * (1.0f + t);
}

__device__ __forceinline__ void gload16(const void* g, void* l) {
  __builtin_amdgcn_global_load_lds((const __attribute__((address_space(1))) void*)g,
                                   (__attribute__((address_space(3))) void*)l, 16, 0, 0);
}

// ---------------- per-k power-of-2 weight scale ----------------
__global__ void rowmax_kernel(const float* __restrict__ w, float* __restrict__ mw) {
  int row = blockIdx.x * 4 + (threadIdx.x >> 6);
  int lane = threadIdx.x & 63;
  const float4* rp = (const float4*)(w + (size_t)row * N_DIM);
  float m = 0.0f;
#pragma unroll
  for (int it = 0; it < 16; ++it) {
    float4 v = rp[it * 64 + lane];
    m = fmaxf(m, fmaxf(fmaxf(fabsf(v.x), fabsf(v.y)), fmaxf(fabsf(v.z), fabsf(v.w))));
  }
#pragma unroll
  for (int off = 32; off > 0; off >>= 1) m = fmaxf(m, __shfl_xor(m, off, 64));
  if (lane == 0) mw[row] = exp2f(rintf(log2f(m)));
}

// ---------------- prep A: one thread per (kg16, m); 16 k-values ----------------
__global__ void prep_a_kernel(const float* __restrict__ inp, signed char* __restrict__ aqi,
                              unsigned char* __restrict__ adf, short* __restrict__ af) {
  int c = blockIdx.x * 256 + threadIdx.x;   // [kg16:64][m:8192]
  int kg = c >> 13, m = c & 8191;
  const float4* src = (const float4*)(inp + (size_t)m * K_DIM + kg * 16);
  float xs[16];
#pragma unroll
  for (int v = 0; v < 4; ++v) {
    float4 t = src[v];
    xs[v * 4 + 0] = t.x; xs[v * 4 + 1] = t.y; xs[v * 4 + 2] = t.z; xs[v * 4 + 3] = t.w;
  }
  int qi[4] = {0, 0, 0, 0};
  unsigned long long f8lo = 0ull, f8hi = 0ull;
  bf16x8 b0, b1;
#pragma unroll
  for (int j = 0; j < 16; ++j) {
    float x = xs[j];
    float s = (x > 0.f) ? 1.f : ((x < 0.f) ? -1.f : 0.f);
    float r = rintf(fabsf(x));
    int iq = (int)(s * fminf(r + 1.f, 7.f));     // in_q, exact small int
    qi[j >> 2] |= (iq & 255) << ((j & 3) * 8);
    unsigned f8 = f2fp8(s * fminf(r, 6.f));      // deq(in_q)
    if (j < 8) f8lo |= (unsigned long long)f8 << (j * 8);
    else       f8hi |= (unsigned long long)f8 << ((j - 8) * 8);
    short bb = f2bf(x);
    if (j < 8) b0[j] = bb; else b1[j - 8] = bb;
  }
  *(i32x4*)(aqi + ((size_t)kg * M_DIM + m) * 16) = (i32x4){qi[0], qi[1], qi[2], qi[3]};
  *(unsigned long long*)(adf + ((size_t)(2 * kg) * M_DIM + m) * 8) = f8lo;
  *(unsigned long long*)(adf + ((size_t)(2 * kg + 1) * M_DIM + m) * 8) = f8hi;
  *(bf16x8*)(af + ((size_t)(2 * kg) * M_DIM + m) * 8) = b0;
  *(bf16x8*)(af + ((size_t)(2 * kg + 1) * M_DIM + m) * 8) = b1;
}

// ---------------- prep W: one thread per (kg16, n) ----------------
__global__ void prep_w_kernel(const float* __restrict__ w, const float* __restrict__ mw,
                              signed char* __restrict__ wqi, unsigned char* __restrict__ wdf,
                              short* __restrict__ wf) {
  int c = blockIdx.x * 256 + threadIdx.x;   // [kg16:64][n:4096]
  int kg = c >> 12, n = c & 4095;
  int qi[4] = {0, 0, 0, 0};
  unsigned long long f8lo = 0ull, f8hi = 0ull;
  bf16x8 b0, b1;
#pragma unroll
  for (int j = 0; j < 16; ++j) {
    float wv = w[(size_t)(kg * 16 + j) * N_DIM + n];
    float sc = mw[kg * 16 + j];                  // wave-uniform
    float s = (wv > 0.f) ? 1.f : ((wv < 0.f) ? -1.f : 0.f);
    float r = rintf(fabsf(wv) * (8.0f / sc));    // exact: 8/sc is a power of 2
    int iq = (int)(s * fminf(r + 1.f, 7.f));     // w_q
    qi[j >> 2] |= (iq & 255) << ((j & 3) * 8);
    unsigned f8 = f2fp8(s * fminf(r, 6.f) * 0.125f * sc);  // deq(w_q), exact in e4m3
    if (j < 8) f8lo |= (unsigned long long)f8 << (j * 8);
    else       f8hi |= (unsigned long long)f8 << ((j - 8) * 8);
    short bb = f2bf(wv);
    if (j < 8) b0[j] = bb; else b1[j - 8] = bb;
  }
  *(i32x4*)(wqi + ((size_t)kg * N_DIM + n) * 16) = (i32x4){qi[0], qi[1], qi[2], qi[3]};
  *(unsigned long long*)(wdf + ((size_t)(2 * kg) * N_DIM + n) * 8) = f8lo;
  *(unsigned long long*)(wdf + ((size_t)(2 * kg + 1) * N_DIM + n) * 8) = f8hi;
  *(bf16x8*)(wf + ((size_t)(2 * kg) * N_DIM + n) * 8) = b0;
  *(bf16x8*)(wf + ((size_t)(2 * kg + 1) * N_DIM + n) * 8) = b1;
}

// ---------------- fused triple GEMM (i8 + fp8 + bf16) + select + GELU ----------------
__global__ __launch_bounds__(256, 2) void fused_gemm_kernel(
    const signed char* __restrict__ aqi, const unsigned char* __restrict__ adf,
    const short* __restrict__ af, const signed char* __restrict__ wqi,
    const unsigned char* __restrict__ wdf, const short* __restrict__ wf,
    const float* __restrict__ bias, float* __restrict__ out) {
  extern __shared__ char lds[];

  const int tid = threadIdx.x;
  const int wid = tid >> 6;   // 0..3
  const int lane = tid & 63;

  // XCD swizzle: 2048 blocks, 8 XCDs -> 256 contiguous tiles per XCD (bijective)
  int bid = blockIdx.x;
  bid = (bid & 7) * 256 + (bid >> 3);
  const int bm0 = (bid >> 5) * 128;   // 64 m-tiles
  const int bn0 = (bid & 31) * 128;   // 32 n-tiles

  const int wr = wid >> 1;   // 0..1 -> 64 rows
  const int wc = wid & 1;    // 0..1 -> 64 cols

  // ---- staging: 32 units of 1KB per K-step buffer, 8 per wave (uniform for vmcnt) ----
  const char* gb[8]; int gs[8]; int lo[8];
#pragma unroll
  for (int i = 0; i < 8; ++i) {
    int u = wid * 8 + i;
    lo[i] = u * 1024 + lane * 16;     // linear LDS destination
    if (u < 4) {                                        // A_i8 [h:2][row:128]x16B
      int o = u * 64 + lane; int h2 = o >> 7, row = o & 127;
      gb[i] = (const char*)aqi + ((size_t)h2 * M_DIM + bm0 + row) * 16;
      gs[i] = 32 * M_DIM;
    } else if (u < 8) {                                 // A_fp8 [kg8:4][row:128]x8B
      int kg = u - 4;
      gb[i] = (const char*)adf + ((size_t)kg * M_DIM + bm0) * 8 + lane * 16;
      gs[i] = 32 * M_DIM;
    } else if (u < 16) {                                // A_bf16 [kg8:4][row:128]x16B
      int o = (u - 8) * 64 + lane; int kg = o >> 7, row = o & 127;
      gb[i] = (const char*)af + ((size_t)kg * M_DIM + bm0 + row) * 16;
      gs[i] = 64 * M_DIM;
    } else if (u < 20) {                                // B_i8 [h:2][col:128]x16B
      int o = (u - 16) * 64 + lane; int h2 = o >> 7, col = o & 127;
      gb[i] = (const char*)wqi + ((size_t)h2 * N_DIM + bn0 + col) * 16;
      gs[i] = 32 * N_DIM;
    } else if (u < 24) {                                // B_fp8 [kg8:4][col:128]x8B
      int kg = u - 20;
      gb[i] = (const char*)wdf + ((size_t)kg * N_DIM + bn0) * 8 + lane * 16;
      gs[i] = 32 * N_DIM;
    } else {                                            // B_bf16 [kg8:4][col:128]x16B
      int o = (u - 24) * 64 + lane; int kg = o >> 7, col = o & 127;
      gb[i] = (const char*)wf + ((size_t)kg * N_DIM + bn0 + col) * 16;
      gs[i] = 64 * N_DIM;
    }
  }

  // fragment geometry (32x32 shapes): row/col = lane&31, k-half h = lane>>5
  const int h = lane >> 5;
  const int l31 = lane & 31;
  const int ra = wr * 64 + l31;
  const int rb = wc * 64 + l31;

  i32x16 acc0[2][2];
  f32x16 acc1[2][2], acc2[2][2];
  const i32x16 zi = {0, 0, 0, 0, 0, 0, 0, 0, 0, 0, 0, 0, 0, 0, 0, 0};
  const f32x16 zf = {0, 0, 0, 0, 0, 0, 0, 0, 0, 0, 0, 0, 0, 0, 0, 0};
#pragma unroll
  for (int mf = 0; mf < 2; ++mf)
#pragma unroll
    for (int nf = 0; nf < 2; ++nf) { acc0[mf][nf] = zi; acc1[mf][nf] = zf; acc2[mf][nf] = zf; }

  // prologue: tile 0 -> buf0
#pragma unroll
  for (int i = 0; i < 8; ++i) gload16(gb[i], lds + lo[i]);

  for (int t = 0; t < 32; ++t) {
    const int cb = (t & 1) * BUF_BYTES;
    if (t < 31) {
      const int nb = ((t + 1) & 1) * BUF_BYTES;
#pragma unroll
      for (int i = 0; i < 8; ++i)
        gload16(gb[i] + (size_t)(t + 1) * gs[i], lds + nb + lo[i]);
      asm volatile("s_waitcnt vmcnt(8)" ::: "memory");  // tile t landed, t+1 in flight
    } else {
      asm volatile("s_waitcnt vmcnt(0)" ::: "memory");
    }
    __builtin_amdgcn_s_barrier();
    __builtin_amdgcn_sched_barrier(0);

    const char* B = lds + cb;
    __builtin_amdgcn_s_setprio(1);
    // ---- q0: i8 sign GEMM (exact) ----
    {
      i32x4 a0[2], b0[2];
#pragma unroll
      for (int mf = 0; mf < 2; ++mf)
        a0[mf] = *(const i32x4*)(B + (h * 128 + ra + mf * 32) * 16);
#pragma unroll
      for (int nf = 0; nf < 2; ++nf)
        b0[nf] = *(const i32x4*)(B + 16384 + (h * 128 + rb + nf * 32) * 16);
#pragma unroll
      for (int mf = 0; mf < 2; ++mf)
#pragma unroll
        for (int nf = 0; nf < 2; ++nf)
          acc0[mf][nf] =
              __builtin_amdgcn_mfma_i32_32x32x32_i8(a0[mf], b0[nf], acc0[mf][nf], 0, 0, 0);
    }
    // ---- q1: fp8 dequant GEMM (exact) ----
#pragma unroll
    for (int kk = 0; kk < 2; ++kk) {
      long a1[2], b1[2];
#pragma unroll
      for (int mf = 0; mf < 2; ++mf)
        a1[mf] = *(const long*)(B + 4096 + ((kk * 2 + h) * 128 + ra + mf * 32) * 8);
#pragma unroll
      for (int nf = 0; nf < 2; ++nf)
        b1[nf] = *(const long*)(B + 20480 + ((kk * 2 + h) * 128 + rb + nf * 32) * 8);
#pragma unroll
      for (int mf = 0; mf < 2; ++mf)
#pragma unroll
        for (int nf = 0; nf < 2; ++nf)
          acc1[mf][nf] = __builtin_amdgcn_mfma_f32_32x32x16_fp8_fp8(a1[mf], b1[nf],
                                                                    acc1[mf][nf], 0, 0, 0);
    }
    // ---- q2: bf16 full GEMM ----
#pragma unroll
    for (int kk = 0; kk < 2; ++kk) {
      bf16x8 a2[2], b2[2];
#pragma unroll
      for (int mf = 0; mf < 2; ++mf)
        a2[mf] = *(const bf16x8*)(B + 8192 + ((kk * 2 + h) * 128 + ra + mf * 32) * 16);
#pragma unroll
      for (int nf = 0; nf < 2; ++nf)
        b2[nf] = *(const bf16x8*)(B + 24576 + ((kk * 2 + h) * 128 + rb + nf * 32) * 16);
#pragma unroll
      for (int mf = 0; mf < 2; ++mf)
#pragma unroll
        for (int nf = 0; nf < 2; ++nf)
          acc2[mf][nf] = __builtin_amdgcn_mfma_f32_32x32x16_bf16(a2[mf], b2[nf],
                                                                 acc2[mf][nf], 0, 0, 0);
    }
    __builtin_amdgcn_s_setprio(0);
    asm volatile("s_waitcnt lgkmcnt(0)" ::: "memory");  // all LDS reads of buf done
    __builtin_amdgcn_sched_barrier(0);
    __builtin_amdgcn_s_barrier();                       // safe to overwrite buf next iter
  }

  // ---- epilogue: select by exact integer sign, bias, GELU ----
  // 32x32 C layout: col = lane&31, row = (reg&3) + 8*(reg>>2) + 4*(lane>>5)
#pragma unroll
  for (int nf = 0; nf < 2; ++nf) {
    const int col = bn0 + rb + nf * 32;
    const float bv = bias[col];
    const float sb = (bv > 0.f) ? 1.f : ((bv < 0.f) ? -1.f : 0.f);
    const float db = sb * fminf(rintf(fabsf(bv)), 6.f);
#pragma unroll
    for (int mf = 0; mf < 2; ++mf) {
#pragma unroll
      for (int r = 0; r < 16; ++r) {
        const int row = bm0 + wr * 64 + mf * 32 + (r & 3) + 8 * (r >> 2) + 4 * h;
        float x = (acc0[mf][nf][r] < 0) ? (acc1[mf][nf][r] + db) : (acc2[mf][nf][r] + bv);
        out[(size_t)row * N_DIM + col] = gelu_f(x);
      }
    }
  }
}

extern "C" void kernel_launch(void* const* d_in, const int* in_sizes, int n_in,
                              void* d_out, int out_size, void* d_ws, size_t ws_size,
                              hipStream_t stream) {
  const float* inp = (const float*)d_in[0];
  const float* w = (const float*)d_in[1];
  const float* bias = (const float*)d_in[2];
  float* out = (float*)d_out;

  // workspace: af 16MB | wf 8MB | aqi 8MB | adf 8MB | wqi 4MB | wdf 4MB | mw 4KB
  char* p = (char*)d_ws;
  short* af = (short*)p;             p += (size_t)M_DIM * K_DIM * 2;
  short* wf = (short*)p;             p += (size_t)K_DIM * N_DIM * 2;
  signed char* aqi = (signed char*)p; p += (size_t)M_DIM * K_DIM;
  unsigned char* adf = (unsigned char*)p; p += (size_t)M_DIM * K_DIM;
  signed char* wqi = (signed char*)p; p += (size_t)K_DIM * N_DIM;
  unsigned char* wdf = (unsigned char*)p; p += (size_t)K_DIM * N_DIM;
  float* mw = (float*)p;

  const int lds_bytes = 2 * BUF_BYTES;  // 65536 -> 2 blocks/CU
  hipFuncSetAttribute((const void*)fused_gemm_kernel,
                      hipFuncAttributeMaxDynamicSharedMemorySize, lds_bytes);

  rowmax_kernel<<<K_DIM / 4, 256, 0, stream>>>(w, mw);
  prep_a_kernel<<<(M_DIM * K_DIM / 16) / 256, 256, 0, stream>>>(inp, aqi, adf, af);
  prep_w_kernel<<<(K_DIM * N_DIM / 16) / 256, 256, 0, stream>>>(w, mw, wqi, wdf, wf);
  fused_gemm_kernel<<<(M_DIM / 128) * (N_DIM / 128), 256, lds_bytes, stream>>>(
      aqi, adf, af, wqi, wdf, wf, bias, out);
}

// Round 7
// 212.956 us; speedup vs baseline: 1.0004x; 1.0001x over previous
//
#include <hip/hip_runtime.h>
#include <hip/hip_bf16.h>

// Problem shape: M = B*S = 8192, K = NX = 1024, N = NF = 4096
#define M_DIM 8192
#define K_DIM 1024
#define N_DIM 4096
// Block tile 128x128, BK=32, 4 waves (2x2), per-wave 64x64 via 32x32 frags.
// LDS buffer 32KB: [0,4K) A_i8 [h:2][row:128]x16B | [4K,8K) A_fp8 [kg8:4][row:128]x8B
// [8K,16K) A_bf16 [kg8:4][row:128]x16B | [16K,20K) B_i8 | [20K,24K) B_fp8 | [24K,32K) B_bf16
// Double-buffered: 64KB -> 2 blocks/CU co-resident (cross-block latency hiding).
#define BUF_BYTES 32768

typedef __attribute__((ext_vector_type(8))) short bf16x8;
typedef __attribute__((ext_vector_type(4))) int i32x4;
typedef __attribute__((ext_vector_type(16))) int i32x16;
typedef __attribute__((ext_vector_type(16))) float f32x16;

__device__ __forceinline__ short f2bf(float f) {
  unsigned u = __builtin_bit_cast(unsigned, f);
  u = (u + 0x7fffu + ((u >> 16) & 1u)) >> 16;
  return (short)u;
}

// f32 -> OCP e4m3fn, exact for our value set (small ints x 2^e)
__device__ __forceinline__ unsigned f2fp8(float v) {
  unsigned b = __builtin_bit_cast(unsigned, v);
  unsigned sg = (b >> 24) & 0x80u;
  unsigned ab = b & 0x7fffffffu;
  if (ab == 0) return sg;
  int e = (int)(ab >> 23) - 127;
  unsigned m3 = (ab >> 20) & 7u;
  if (e >= -6) return sg | (unsigned)((e + 7) << 3) | m3;
  return sg | ((8u + m3) >> (-6 - e));  // subnormal (exact for our values)
}

__device__ __forceinline__ float gelu_f(float x) {
  float u = 0.7978845608028654f * (x + 0.044715f * x * x * x);
  float e = __expf(2.0f * u);
  float t = 1.0f - 2.0f / (e + 1.0f);
  return 0.5f * x * (1.0f + t);
}

__device__ __forceinline__ void gload16(const void* g, void* l) {
  __builtin_amdgcn_global_load_lds((const __attribute__((address_space(1))) void*)g,
                                   (__attribute__((address_space(3))) void*)l, 16, 0, 0);
}

// ---------------- per-k power-of-2 weight scale ----------------
__global__ void rowmax_kernel(const float* __restrict__ w, float* __restrict__ mw) {
  int row = blockIdx.x * 4 + (threadIdx.x >> 6);
  int lane = threadIdx.x & 63;
  const float4* rp = (const float4*)(w + (size_t)row * N_DIM);
  float m = 0.0f;
#pragma unroll
  for (int it = 0; it < 16; ++it) {
    float4 v = rp[it * 64 + lane];
    m = fmaxf(m, fmaxf(fmaxf(fabsf(v.x), fabsf(v.y)), fmaxf(fabsf(v.z), fabsf(v.w))));
  }
#pragma unroll
  for (int off = 32; off > 0; off >>= 1) m = fmaxf(m, __shfl_xor(m, off, 64));
  if (lane == 0) mw[row] = exp2f(rintf(log2f(m)));
}

// ---------------- prep A: one thread per (kg16, m); 16 k-values ----------------
__global__ void prep_a_kernel(const float* __restrict__ inp, signed char* __restrict__ aqi,
                              unsigned char* __restrict__ adf, short* __restrict__ af) {
  int c = blockIdx.x * 256 + threadIdx.x;   // [kg16:64][m:8192]
  int kg = c >> 13, m = c & 8191;
  const float4* src = (const float4*)(inp + (size_t)m * K_DIM + kg * 16);
  float xs[16];
#pragma unroll
  for (int v = 0; v < 4; ++v) {
    float4 t = src[v];
    xs[v * 4 + 0] = t.x; xs[v * 4 + 1] = t.y; xs[v * 4 + 2] = t.z; xs[v * 4 + 3] = t.w;
  }
  int qi[4] = {0, 0, 0, 0};
  unsigned long long f8lo = 0ull, f8hi = 0ull;
  bf16x8 b0, b1;
#pragma unroll
  for (int j = 0; j < 16; ++j) {
    float x = xs[j];
    float s = (x > 0.f) ? 1.f : ((x < 0.f) ? -1.f : 0.f);
    float r = rintf(fabsf(x));
    int iq = (int)(s * fminf(r + 1.f, 7.f));     // in_q, exact small int
    qi[j >> 2] |= (iq & 255) << ((j & 3) * 8);
    unsigned f8 = f2fp8(s * fminf(r, 6.f));      // deq(in_q)
    if (j < 8) f8lo |= (unsigned long long)f8 << (j * 8);
    else       f8hi |= (unsigned long long)f8 << ((j - 8) * 8);
    short bb = f2bf(x);
    if (j < 8) b0[j] = bb; else b1[j - 8] = bb;
  }
  *(i32x4*)(aqi + ((size_t)kg * M_DIM + m) * 16) = (i32x4){qi[0], qi[1], qi[2], qi[3]};
  *(unsigned long long*)(adf + ((size_t)(2 * kg) * M_DIM + m) * 8) = f8lo;
  *(unsigned long long*)(adf + ((size_t)(2 * kg + 1) * M_DIM + m) * 8) = f8hi;
  *(bf16x8*)(af + ((size_t)(2 * kg) * M_DIM + m) * 8) = b0;
  *(bf16x8*)(af + ((size_t)(2 * kg + 1) * M_DIM + m) * 8) = b1;
}

// ---------------- prep W: one thread per (kg16, n) ----------------
__global__ void prep_w_kernel(const float* __restrict__ w, const float* __restrict__ mw,
                              signed char* __restrict__ wqi, unsigned char* __restrict__ wdf,
                              short* __restrict__ wf) {
  int c = blockIdx.x * 256 + threadIdx.x;   // [kg16:64][n:4096]
  int kg = c >> 12, n = c & 4095;
  int qi[4] = {0, 0, 0, 0};
  unsigned long long f8lo = 0ull, f8hi = 0ull;
  bf16x8 b0, b1;
#pragma unroll
  for (int j = 0; j < 16; ++j) {
    float wv = w[(size_t)(kg * 16 + j) * N_DIM + n];
    float sc = mw[kg * 16 + j];                  // wave-uniform
    float s = (wv > 0.f) ? 1.f : ((wv < 0.f) ? -1.f : 0.f);
    float r = rintf(fabsf(wv) * (8.0f / sc));    // exact: 8/sc is a power of 2
    int iq = (int)(s * fminf(r + 1.f, 7.f));     // w_q
    qi[j >> 2] |= (iq & 255) << ((j & 3) * 8);
    unsigned f8 = f2fp8(s * fminf(r, 6.f) * 0.125f * sc);  // deq(w_q), exact in e4m3
    if (j < 8) f8lo |= (unsigned long long)f8 << (j * 8);
    else       f8hi |= (unsigned long long)f8 << ((j - 8) * 8);
    short bb = f2bf(wv);
    if (j < 8) b0[j] = bb; else b1[j - 8] = bb;
  }
  *(i32x4*)(wqi + ((size_t)kg * N_DIM + n) * 16) = (i32x4){qi[0], qi[1], qi[2], qi[3]};
  *(unsigned long long*)(wdf + ((size_t)(2 * kg) * N_DIM + n) * 8) = f8lo;
  *(unsigned long long*)(wdf + ((size_t)(2 * kg + 1) * N_DIM + n) * 8) = f8hi;
  *(bf16x8*)(wf + ((size_t)(2 * kg) * N_DIM + n) * 8) = b0;
  *(bf16x8*)(wf + ((size_t)(2 * kg + 1) * N_DIM + n) * 8) = b1;
}

// ---------------- fused triple GEMM (i8 + fp8 + bf16) + select + GELU ----------------
__global__ __launch_bounds__(256, 2) void fused_gemm_kernel(
    const signed char* __restrict__ aqi, const unsigned char* __restrict__ adf,
    const short* __restrict__ af, const signed char* __restrict__ wqi,
    const unsigned char* __restrict__ wdf, const short* __restrict__ wf,
    const float* __restrict__ bias, float* __restrict__ out) {
  extern __shared__ char lds[];

  const int tid = threadIdx.x;
  const int wid = tid >> 6;   // 0..3
  const int lane = tid & 63;

  // XCD swizzle: 2048 blocks, 8 XCDs -> 256 contiguous tiles per XCD (bijective)
  int bid = blockIdx.x;
  bid = (bid & 7) * 256 + (bid >> 3);
  const int bm0 = (bid >> 5) * 128;   // 64 m-tiles
  const int bn0 = (bid & 31) * 128;   // 32 n-tiles

  const int wr = wid >> 1;   // 0..1 -> 64 rows
  const int wc = wid & 1;    // 0..1 -> 64 cols

  // ---- staging: 32 units of 1KB per K-step buffer, 8 per wave (uniform for vmcnt) ----
  const char* gb[8]; int gs[8]; int lo[8];
#pragma unroll
  for (int i = 0; i < 8; ++i) {
    int u = wid * 8 + i;
    lo[i] = u * 1024 + lane * 16;     // linear LDS destination
    if (u < 4) {                                        // A_i8 [h:2][row:128]x16B
      int o = u * 64 + lane; int h2 = o >> 7, row = o & 127;
      gb[i] = (const char*)aqi + ((size_t)h2 * M_DIM + bm0 + row) * 16;
      gs[i] = 32 * M_DIM;
    } else if (u < 8) {                                 // A_fp8 [kg8:4][row:128]x8B
      int kg = u - 4;
      gb[i] = (const char*)adf + ((size_t)kg * M_DIM + bm0) * 8 + lane * 16;
      gs[i] = 32 * M_DIM;
    } else if (u < 16) {                                // A_bf16 [kg8:4][row:128]x16B
      int o = (u - 8) * 64 + lane; int kg = o >> 7, row = o & 127;
      gb[i] = (const char*)af + ((size_t)kg * M_DIM + bm0 + row) * 16;
      gs[i] = 64 * M_DIM;
    } else if (u < 20) {                                // B_i8 [h:2][col:128]x16B
      int o = (u - 16) * 64 + lane; int h2 = o >> 7, col = o & 127;
      gb[i] = (const char*)wqi + ((size_t)h2 * N_DIM + bn0 + col) * 16;
      gs[i] = 32 * N_DIM;
    } else if (u < 24) {                                // B_fp8 [kg8:4][col:128]x8B
      int kg = u - 20;
      gb[i] = (const char*)wdf + ((size_t)kg * N_DIM + bn0) * 8 + lane * 16;
      gs[i] = 32 * N_DIM;
    } else {                                            // B_bf16 [kg8:4][col:128]x16B
      int o = (u - 24) * 64 + lane; int kg = o >> 7, col = o & 127;
      gb[i] = (const char*)wf + ((size_t)kg * N_DIM + bn0 + col) * 16;
      gs[i] = 64 * N_DIM;
    }
  }

  // fragment geometry (32x32 shapes): row/col = lane&31, k-half h = lane>>5
  const int h = lane >> 5;
  const int l31 = lane & 31;
  const int ra = wr * 64 + l31;
  const int rb = wc * 64 + l31;

  i32x16 acc0[2][2];
  f32x16 acc1[2][2], acc2[2][2];
  const i32x16 zi = {0, 0, 0, 0, 0, 0, 0, 0, 0, 0, 0, 0, 0, 0, 0, 0};
  const f32x16 zf = {0, 0, 0, 0, 0, 0, 0, 0, 0, 0, 0, 0, 0, 0, 0, 0};
#pragma unroll
  for (int mf = 0; mf < 2; ++mf)
#pragma unroll
    for (int nf = 0; nf < 2; ++nf) { acc0[mf][nf] = zi; acc1[mf][nf] = zf; acc2[mf][nf] = zf; }

  // prologue: tile 0 -> buf0
#pragma unroll
  for (int i = 0; i < 8; ++i) gload16(gb[i], lds + lo[i]);

  for (int t = 0; t < 32; ++t) {
    const int cb = (t & 1) * BUF_BYTES;
    if (t < 31) {
      const int nb = ((t + 1) & 1) * BUF_BYTES;
#pragma unroll
      for (int i = 0; i < 8; ++i)
        gload16(gb[i] + (size_t)(t + 1) * gs[i], lds + nb + lo[i]);
      asm volatile("s_waitcnt vmcnt(8)" ::: "memory");  // tile t landed, t+1 in flight
    } else {
      asm volatile("s_waitcnt vmcnt(0)" ::: "memory");
    }
    __builtin_amdgcn_s_barrier();
    __builtin_amdgcn_sched_barrier(0);

    const char* B = lds + cb;
    __builtin_amdgcn_s_setprio(1);
    // ---- q0: i8 sign GEMM (exact) ----
    {
      i32x4 a0[2], b0[2];
#pragma unroll
      for (int mf = 0; mf < 2; ++mf)
        a0[mf] = *(const i32x4*)(B + (h * 128 + ra + mf * 32) * 16);
#pragma unroll
      for (int nf = 0; nf < 2; ++nf)
        b0[nf] = *(const i32x4*)(B + 16384 + (h * 128 + rb + nf * 32) * 16);
#pragma unroll
      for (int mf = 0; mf < 2; ++mf)
#pragma unroll
        for (int nf = 0; nf < 2; ++nf)
          acc0[mf][nf] =
              __builtin_amdgcn_mfma_i32_32x32x32_i8(a0[mf], b0[nf], acc0[mf][nf], 0, 0, 0);
    }
    // ---- q1: fp8 dequant GEMM (exact) ----
#pragma unroll
    for (int kk = 0; kk < 2; ++kk) {
      long a1[2], b1[2];
#pragma unroll
      for (int mf = 0; mf < 2; ++mf)
        a1[mf] = *(const long*)(B + 4096 + ((kk * 2 + h) * 128 + ra + mf * 32) * 8);
#pragma unroll
      for (int nf = 0; nf < 2; ++nf)
        b1[nf] = *(const long*)(B + 20480 + ((kk * 2 + h) * 128 + rb + nf * 32) * 8);
#pragma unroll
      for (int mf = 0; mf < 2; ++mf)
#pragma unroll
        for (int nf = 0; nf < 2; ++nf)
          acc1[mf][nf] = __builtin_amdgcn_mfma_f32_32x32x16_fp8_fp8(a1[mf], b1[nf],
                                                                    acc1[mf][nf], 0, 0, 0);
    }
    // ---- q2: bf16 full GEMM ----
#pragma unroll
    for (int kk = 0; kk < 2; ++kk) {
      bf16x8 a2[2], b2[2];
#pragma unroll
      for (int mf = 0; mf < 2; ++mf)
        a2[mf] = *(const bf16x8*)(B + 8192 + ((kk * 2 + h) * 128 + ra + mf * 32) * 16);
#pragma unroll
      for (int nf = 0; nf < 2; ++nf)
        b2[nf] = *(const bf16x8*)(B + 24576 + ((kk * 2 + h) * 128 + rb + nf * 32) * 16);
#pragma unroll
      for (int mf = 0; mf < 2; ++mf)
#pragma unroll
        for (int nf = 0; nf < 2; ++nf)
          acc2[mf][nf] = __builtin_amdgcn_mfma_f32_32x32x16_bf16(a2[mf], b2[nf],
                                                                 acc2[mf][nf], 0, 0, 0);
    }
    __builtin_amdgcn_s_setprio(0);
    asm volatile("s_waitcnt lgkmcnt(0)" ::: "memory");  // all LDS reads of buf done
    __builtin_amdgcn_sched_barrier(0);
    __builtin_amdgcn_s_barrier();                       // safe to overwrite buf next iter
  }

  // ---- epilogue: select by exact integer sign, bias, GELU ----
  // 32x32 C layout: col = lane&31, row = (reg&3) + 8*(reg>>2) + 4*(lane>>5)
#pragma unroll
  for (int nf = 0; nf < 2; ++nf) {
    const int col = bn0 + rb + nf * 32;
    const float bv = bias[col];
    const float sb = (bv > 0.f) ? 1.f : ((bv < 0.f) ? -1.f : 0.f);
    const float db = sb * fminf(rintf(fabsf(bv)), 6.f);
#pragma unroll
    for (int mf = 0; mf < 2; ++mf) {
#pragma unroll
      for (int r = 0; r < 16; ++r) {
        const int row = bm0 + wr * 64 + mf * 32 + (r & 3) + 8 * (r >> 2) + 4 * h;
        float x = (acc0[mf][nf][r] < 0) ? (acc1[mf][nf][r] + db) : (acc2[mf][nf][r] + bv);
        out[(size_t)row * N_DIM + col] = gelu_f(x);
      }
    }
  }
}

extern "C" void kernel_launch(void* const* d_in, const int* in_sizes, int n_in,
                              void* d_out, int out_size, void* d_ws, size_t ws_size,
                              hipStream_t stream) {
  const float* inp = (const float*)d_in[0];
  const float* w = (const float*)d_in[1];
  const float* bias = (const float*)d_in[2];
  float* out = (float*)d_out;

  // workspace: af 16MB | wf 8MB | aqi 8MB | adf 8MB | wqi 4MB | wdf 4MB | mw 4KB
  char* p = (char*)d_ws;
  short* af = (short*)p;             p += (size_t)M_DIM * K_DIM * 2;
  short* wf = (short*)p;             p += (size_t)K_DIM * N_DIM * 2;
  signed char* aqi = (signed char*)p; p += (size_t)M_DIM * K_DIM;
  unsigned char* adf = (unsigned char*)p; p += (size_t)M_DIM * K_DIM;
  signed char* wqi = (signed char*)p; p += (size_t)K_DIM * N_DIM;
  unsigned char* wdf = (unsigned char*)p; p += (size_t)K_DIM * N_DIM;
  float* mw = (float*)p;

  const int lds_bytes = 2 * BUF_BYTES;  // 65536 -> 2 blocks/CU
  hipFuncSetAttribute((const void*)fused_gemm_kernel,
                      hipFuncAttributeMaxDynamicSharedMemorySize, lds_bytes);

  rowmax_kernel<<<K_DIM / 4, 256, 0, stream>>>(w, mw);
  prep_a_kernel<<<(M_DIM * K_DIM / 16) / 256, 256, 0, stream>>>(inp, aqi, adf, af);
  prep_w_kernel<<<(K_DIM * N_DIM / 16) / 256, 256, 0, stream>>>(w, mw, wqi, wdf, wf);
  fused_gemm_kernel<<<(M_DIM / 128) * (N_DIM / 128), 256, lds_bytes, stream>>>(
      aqi, adf, af, wqi, wdf, wf, bias, out);
}

// Round 8
// 212.607 us; speedup vs baseline: 1.0021x; 1.0016x over previous
//
#include <hip/hip_runtime.h>
#include <hip/hip_bf16.h>

// Problem shape: M = B*S = 8192, K = NX = 1024, N = NF = 4096
#define M_DIM 8192
#define K_DIM 1024
#define N_DIM 4096
// Block tile 128x128, BK=32, 4 waves (2x2), per-wave 64x64 via 32x32 frags.
// LDS buffer 32KB: [0,4K) A_i8 [h:2][row:128]x16B | [4K,8K) A_fp8 [kg8:4][row:128]x8B
// [8K,16K) A_bf16 [kg8:4][row:128]x16B | [16K,20K) B_i8 | [20K,24K) B_fp8 | [24K,32K) B_bf16
// Double-buffered: 64KB -> 2 blocks/CU co-resident (cross-block latency hiding).
#define BUF_BYTES 32768

typedef __attribute__((ext_vector_type(8))) short bf16x8;
typedef __attribute__((ext_vector_type(4))) int i32x4;
typedef __attribute__((ext_vector_type(16))) int i32x16;
typedef __attribute__((ext_vector_type(16))) float f32x16;

__device__ __forceinline__ short f2bf(float f) {
  unsigned u = __builtin_bit_cast(unsigned, f);
  u = (u + 0x7fffu + ((u >> 16) & 1u)) >> 16;
  return (short)u;
}

// f32 -> OCP e4m3fn, exact for our value set (small ints x 2^e)
__device__ __forceinline__ unsigned f2fp8(float v) {
  unsigned b = __builtin_bit_cast(unsigned, v);
  unsigned sg = (b >> 24) & 0x80u;
  unsigned ab = b & 0x7fffffffu;
  if (ab == 0) return sg;
  int e = (int)(ab >> 23) - 127;
  unsigned m3 = (ab >> 20) & 7u;
  if (e >= -6) return sg | (unsigned)((e + 7) << 3) | m3;
  return sg | ((8u + m3) >> (-6 - e));  // subnormal (exact for our values)
}

__device__ __forceinline__ float gelu_f(float x) {
  float u = 0.7978845608028654f * (x + 0.044715f * x * x * x);
  float e = __expf(2.0f * u);
  float t = 1.0f - 2.0f / (e + 1.0f);
  return 0.5f * x * (1.0f + t);
}

__device__ __forceinline__ void gload16(const void* g, void* l) {
  __builtin_amdgcn_global_load_lds((const __attribute__((address_space(1))) void*)g,
                                   (__attribute__((address_space(3))) void*)l, 16, 0, 0);
}

// ---------------- per-k power-of-2 weight scale ----------------
__global__ void rowmax_kernel(const float* __restrict__ w, float* __restrict__ mw) {
  int row = blockIdx.x * 4 + (threadIdx.x >> 6);
  int lane = threadIdx.x & 63;
  const float4* rp = (const float4*)(w + (size_t)row * N_DIM);
  float m = 0.0f;
#pragma unroll
  for (int it = 0; it < 16; ++it) {
    float4 v = rp[it * 64 + lane];
    m = fmaxf(m, fmaxf(fmaxf(fabsf(v.x), fabsf(v.y)), fmaxf(fabsf(v.z), fabsf(v.w))));
  }
#pragma unroll
  for (int off = 32; off > 0; off >>= 1) m = fmaxf(m, __shfl_xor(m, off, 64));
  if (lane == 0) mw[row] = exp2f(rintf(log2f(m)));
}

// ---------------- prep A: one thread per (kg16, m); 16 k-values ----------------
__global__ void prep_a_kernel(const float* __restrict__ inp, signed char* __restrict__ aqi,
                              unsigned char* __restrict__ adf, short* __restrict__ af) {
  int c = blockIdx.x * 256 + threadIdx.x;   // [kg16:64][m:8192]
  int kg = c >> 13, m = c & 8191;
  const float4* src = (const float4*)(inp + (size_t)m * K_DIM + kg * 16);
  float xs[16];
#pragma unroll
  for (int v = 0; v < 4; ++v) {
    float4 t = src[v];
    xs[v * 4 + 0] = t.x; xs[v * 4 + 1] = t.y; xs[v * 4 + 2] = t.z; xs[v * 4 + 3] = t.w;
  }
  int qi[4] = {0, 0, 0, 0};
  unsigned long long f8lo = 0ull, f8hi = 0ull;
  bf16x8 b0, b1;
#pragma unroll
  for (int j = 0; j < 16; ++j) {
    float x = xs[j];
    float s = (x > 0.f) ? 1.f : ((x < 0.f) ? -1.f : 0.f);
    float r = rintf(fabsf(x));
    int iq = (int)(s * fminf(r + 1.f, 7.f));     // in_q, exact small int
    qi[j >> 2] |= (iq & 255) << ((j & 3) * 8);
    unsigned f8 = f2fp8(s * fminf(r, 6.f));      // deq(in_q)
    if (j < 8) f8lo |= (unsigned long long)f8 << (j * 8);
    else       f8hi |= (unsigned long long)f8 << ((j - 8) * 8);
    short bb = f2bf(x);
    if (j < 8) b0[j] = bb; else b1[j - 8] = bb;
  }
  *(i32x4*)(aqi + ((size_t)kg * M_DIM + m) * 16) = (i32x4){qi[0], qi[1], qi[2], qi[3]};
  *(unsigned long long*)(adf + ((size_t)(2 * kg) * M_DIM + m) * 8) = f8lo;
  *(unsigned long long*)(adf + ((size_t)(2 * kg + 1) * M_DIM + m) * 8) = f8hi;
  *(bf16x8*)(af + ((size_t)(2 * kg) * M_DIM + m) * 8) = b0;
  *(bf16x8*)(af + ((size_t)(2 * kg + 1) * M_DIM + m) * 8) = b1;
}

// ---------------- prep W: one thread per (kg16, n) ----------------
__global__ void prep_w_kernel(const float* __restrict__ w, const float* __restrict__ mw,
                              signed char* __restrict__ wqi, unsigned char* __restrict__ wdf,
                              short* __restrict__ wf) {
  int c = blockIdx.x * 256 + threadIdx.x;   // [kg16:64][n:4096]
  int kg = c >> 12, n = c & 4095;
  int qi[4] = {0, 0, 0, 0};
  unsigned long long f8lo = 0ull, f8hi = 0ull;
  bf16x8 b0, b1;
#pragma unroll
  for (int j = 0; j < 16; ++j) {
    float wv = w[(size_t)(kg * 16 + j) * N_DIM + n];
    float sc = mw[kg * 16 + j];                  // wave-uniform
    float s = (wv > 0.f) ? 1.f : ((wv < 0.f) ? -1.f : 0.f);
    float r = rintf(fabsf(wv) * (8.0f / sc));    // exact: 8/sc is a power of 2
    int iq = (int)(s * fminf(r + 1.f, 7.f));     // w_q
    qi[j >> 2] |= (iq & 255) << ((j & 3) * 8);
    unsigned f8 = f2fp8(s * fminf(r, 6.f) * 0.125f * sc);  // deq(w_q), exact in e4m3
    if (j < 8) f8lo |= (unsigned long long)f8 << (j * 8);
    else       f8hi |= (unsigned long long)f8 << ((j - 8) * 8);
    short bb = f2bf(wv);
    if (j < 8) b0[j] = bb; else b1[j - 8] = bb;
  }
  *(i32x4*)(wqi + ((size_t)kg * N_DIM + n) * 16) = (i32x4){qi[0], qi[1], qi[2], qi[3]};
  *(unsigned long long*)(wdf + ((size_t)(2 * kg) * N_DIM + n) * 8) = f8lo;
  *(unsigned long long*)(wdf + ((size_t)(2 * kg + 1) * N_DIM + n) * 8) = f8hi;
  *(bf16x8*)(wf + ((size_t)(2 * kg) * N_DIM + n) * 8) = b0;
  *(bf16x8*)(wf + ((size_t)(2 * kg + 1) * N_DIM + n) * 8) = b1;
}

// ---------------- fused triple GEMM (i8 + fp8 + bf16) + select + GELU ----------------
__global__ __launch_bounds__(256, 2) void fused_gemm_kernel(
    const signed char* __restrict__ aqi, const unsigned char* __restrict__ adf,
    const short* __restrict__ af, const signed char* __restrict__ wqi,
    const unsigned char* __restrict__ wdf, const short* __restrict__ wf,
    const float* __restrict__ bias, float* __restrict__ out) {
  extern __shared__ char lds[];

  const int tid = threadIdx.x;
  const int wid = tid >> 6;   // 0..3
  const int lane = tid & 63;

  // XCD swizzle: 2048 blocks, 8 XCDs -> 256 contiguous tiles per XCD (bijective)
  int bid = blockIdx.x;
  bid = (bid & 7) * 256 + (bid >> 3);
  const int bm0 = (bid >> 5) * 128;   // 64 m-tiles
  const int bn0 = (bid & 31) * 128;   // 32 n-tiles

  const int wr = wid >> 1;   // 0..1 -> 64 rows
  const int wc = wid & 1;    // 0..1 -> 64 cols

  // ---- staging: 32 units of 1KB per K-step buffer, 8 per wave (uniform for vmcnt) ----
  const char* gb[8]; int gs[8]; int lo[8];
#pragma unroll
  for (int i = 0; i < 8; ++i) {
    int u = wid * 8 + i;
    lo[i] = u * 1024 + lane * 16;     // linear LDS destination
    if (u < 4) {                                        // A_i8 [h:2][row:128]x16B
      int o = u * 64 + lane; int h2 = o >> 7, row = o & 127;
      gb[i] = (const char*)aqi + ((size_t)h2 * M_DIM + bm0 + row) * 16;
      gs[i] = 32 * M_DIM;
    } else if (u < 8) {                                 // A_fp8 [kg8:4][row:128]x8B
      int kg = u - 4;
      gb[i] = (const char*)adf + ((size_t)kg * M_DIM + bm0) * 8 + lane * 16;
      gs[i] = 32 * M_DIM;
    } else if (u < 16) {                                // A_bf16 [kg8:4][row:128]x16B
      int o = (u - 8) * 64 + lane; int kg = o >> 7, row = o & 127;
      gb[i] = (const char*)af + ((size_t)kg * M_DIM + bm0 + row) * 16;
      gs[i] = 64 * M_DIM;
    } else if (u < 20) {                                // B_i8 [h:2][col:128]x16B
      int o = (u - 16) * 64 + lane; int h2 = o >> 7, col = o & 127;
      gb[i] = (const char*)wqi + ((size_t)h2 * N_DIM + bn0 + col) * 16;
      gs[i] = 32 * N_DIM;
    } else if (u < 24) {                                // B_fp8 [kg8:4][col:128]x8B
      int kg = u - 20;
      gb[i] = (const char*)wdf + ((size_t)kg * N_DIM + bn0) * 8 + lane * 16;
      gs[i] = 32 * N_DIM;
    } else {                                            // B_bf16 [kg8:4][col:128]x16B
      int o = (u - 24) * 64 + lane; int kg = o >> 7, col = o & 127;
      gb[i] = (const char*)wf + ((size_t)kg * N_DIM + bn0 + col) * 16;
      gs[i] = 64 * N_DIM;
    }
  }

  // fragment geometry (32x32 shapes): row/col = lane&31, k-half h = lane>>5
  const int h = lane >> 5;
  const int l31 = lane & 31;
  const int ra = wr * 64 + l31;
  const int rb = wc * 64 + l31;

  i32x16 acc0[2][2];
  f32x16 acc1[2][2], acc2[2][2];
  const i32x16 zi = {0, 0, 0, 0, 0, 0, 0, 0, 0, 0, 0, 0, 0, 0, 0, 0};
  const f32x16 zf = {0, 0, 0, 0, 0, 0, 0, 0, 0, 0, 0, 0, 0, 0, 0, 0};
#pragma unroll
  for (int mf = 0; mf < 2; ++mf)
#pragma unroll
    for (int nf = 0; nf < 2; ++nf) { acc0[mf][nf] = zi; acc1[mf][nf] = zf; acc2[mf][nf] = zf; }

  // prologue: tile 0 -> buf0
#pragma unroll
  for (int i = 0; i < 8; ++i) gload16(gb[i], lds + lo[i]);

  for (int t = 0; t < 32; ++t) {
    const int cb = (t & 1) * BUF_BYTES;
    if (t < 31) {
      const int nb = ((t + 1) & 1) * BUF_BYTES;
#pragma unroll
      for (int i = 0; i < 8; ++i)
        gload16(gb[i] + (size_t)(t + 1) * gs[i], lds + nb + lo[i]);
      asm volatile("s_waitcnt vmcnt(8)" ::: "memory");  // tile t landed, t+1 in flight
    } else {
      asm volatile("s_waitcnt vmcnt(0)" ::: "memory");
    }
    __builtin_amdgcn_s_barrier();
    __builtin_amdgcn_sched_barrier(0);

    const char* B = lds + cb;
    __builtin_amdgcn_s_setprio(1);
    // ---- q0: i8 sign GEMM (exact) ----
    {
      i32x4 a0[2], b0[2];
#pragma unroll
      for (int mf = 0; mf < 2; ++mf)
        a0[mf] = *(const i32x4*)(B + (h * 128 + ra + mf * 32) * 16);
#pragma unroll
      for (int nf = 0; nf < 2; ++nf)
        b0[nf] = *(const i32x4*)(B + 16384 + (h * 128 + rb + nf * 32) * 16);
#pragma unroll
      for (int mf = 0; mf < 2; ++mf)
#pragma unroll
        for (int nf = 0; nf < 2; ++nf)
          acc0[mf][nf] =
              __builtin_amdgcn_mfma_i32_32x32x32_i8(a0[mf], b0[nf], acc0[mf][nf], 0, 0, 0);
    }
    // ---- q1: fp8 dequant GEMM (exact) ----
#pragma unroll
    for (int kk = 0; kk < 2; ++kk) {
      long a1[2], b1[2];
#pragma unroll
      for (int mf = 0; mf < 2; ++mf)
        a1[mf] = *(const long*)(B + 4096 + ((kk * 2 + h) * 128 + ra + mf * 32) * 8);
#pragma unroll
      for (int nf = 0; nf < 2; ++nf)
        b1[nf] = *(const long*)(B + 20480 + ((kk * 2 + h) * 128 + rb + nf * 32) * 8);
#pragma unroll
      for (int mf = 0; mf < 2; ++mf)
#pragma unroll
        for (int nf = 0; nf < 2; ++nf)
          acc1[mf][nf] = __builtin_amdgcn_mfma_f32_32x32x16_fp8_fp8(a1[mf], b1[nf],
                                                                    acc1[mf][nf], 0, 0, 0);
    }
    // ---- q2: bf16 full GEMM ----
#pragma unroll
    for (int kk = 0; kk < 2; ++kk) {
      bf16x8 a2[2], b2[2];
#pragma unroll
      for (int mf = 0; mf < 2; ++mf)
        a2[mf] = *(const bf16x8*)(B + 8192 + ((kk * 2 + h) * 128 + ra + mf * 32) * 16);
#pragma unroll
      for (int nf = 0; nf < 2; ++nf)
        b2[nf] = *(const bf16x8*)(B + 24576 + ((kk * 2 + h) * 128 + rb + nf * 32) * 16);
#pragma unroll
      for (int mf = 0; mf < 2; ++mf)
#pragma unroll
        for (int nf = 0; nf < 2; ++nf)
          acc2[mf][nf] = __builtin_amdgcn_mfma_f32_32x32x16_bf16(a2[mf], b2[nf],
                                                                 acc2[mf][nf], 0, 0, 0);
    }
    __builtin_amdgcn_s_setprio(0);
    asm volatile("s_waitcnt lgkmcnt(0)" ::: "memory");  // all LDS reads of buf done
    __builtin_amdgcn_sched_barrier(0);
    __builtin_amdgcn_s_barrier();                       // safe to overwrite buf next iter
  }

  // ---- epilogue: select by exact integer sign, bias, GELU ----
  // 32x32 C layout: col = lane&31, row = (reg&3) + 8*(reg>>2) + 4*(lane>>5)
#pragma unroll
  for (int nf = 0; nf < 2; ++nf) {
    const int col = bn0 + rb + nf * 32;
    const float bv = bias[col];
    const float sb = (bv > 0.f) ? 1.f : ((bv < 0.f) ? -1.f : 0.f);
    const float db = sb * fminf(rintf(fabsf(bv)), 6.f);
#pragma unroll
    for (int mf = 0; mf < 2; ++mf) {
#pragma unroll
      for (int r = 0; r < 16; ++r) {
        const int row = bm0 + wr * 64 + mf * 32 + (r & 3) + 8 * (r >> 2) + 4 * h;
        float x = (acc0[mf][nf][r] < 0) ? (acc1[mf][nf][r] + db) : (acc2[mf][nf][r] + bv);
        out[(size_t)row * N_DIM + col] = gelu_f(x);
      }
    }
  }
}

extern "C" void kernel_launch(void* const* d_in, const int* in_sizes, int n_in,
                              void* d_out, int out_size, void* d_ws, size_t ws_size,
                              hipStream_t stream) {
  const float* inp = (const float*)d_in[0];
  const float* w = (const float*)d_in[1];
  const float* bias = (const float*)d_in[2];
  float* out = (float*)d_out;

  // workspace: af 16MB | wf 8MB | aqi 8MB | adf 8MB | wqi 4MB | wdf 4MB | mw 4KB
  char* p = (char*)d_ws;
  short* af = (short*)p;             p += (size_t)M_DIM * K_DIM * 2;
  short* wf = (short*)p;             p += (size_t)K_DIM * N_DIM * 2;
  signed char* aqi = (signed char*)p; p += (size_t)M_DIM * K_DIM;
  unsigned char* adf = (unsigned char*)p; p += (size_t)M_DIM * K_DIM;
  signed char* wqi = (signed char*)p; p += (size_t)K_DIM * N_DIM;
  unsigned char* wdf = (unsigned char*)p; p += (size_t)K_DIM * N_DIM;
  float* mw = (float*)p;

  const int lds_bytes = 2 * BUF_BYTES;  // 65536 -> 2 blocks/CU
  hipFuncSetAttribute((const void*)fused_gemm_kernel,
                      hipFuncAttributeMaxDynamicSharedMemorySize, lds_bytes);

  rowmax_kernel<<<K_DIM / 4, 256, 0, stream>>>(w, mw);
  prep_a_kernel<<<(M_DIM * K_DIM / 16) / 256, 256, 0, stream>>>(inp, aqi, adf, af);
  prep_w_kernel<<<(K_DIM * N_DIM / 16) / 256, 256, 0, stream>>>(w, mw, wqi, wdf, wf);
  fused_gemm_kernel<<<(M_DIM / 128) * (N_DIM / 128), 256, lds_bytes, stream>>>(
      aqi, adf, af, wqi, wdf, wf, bias, out);
}